// Round 8
// baseline (86.503 us; speedup 1.0000x reference)
//
#include <hip/hip_runtime.h>

#define BB 8
#define CC 512
#define NH 8
#define HD 64
#define HH 96
#define WW 96
#define AMP 3
#define KS 7
#define TH 16
#define TW 32
#define NTHR 256
#define HALO_H (TH + 2*AMP)      // 22
#define NCOL 40                  // staged cols: w0-4 .. w0+35
#define ROWH2 88                 // 80 used + 8 pad: 22x16B rows -> distinct bank groups
#define LKSZ (HALO_H * ROWH2)    // 1936 h2 per buffer
#define NCHUNK 16                // 64 d / 4 per chunk
#define PLANE (HH * WW)          // 9216
#define NPLANE (NH * PLANE)      // 73728
#define NTOT (BB * CC * PLANE)
#define TASKS (HALO_H * 10)      // 220 staging tasks (4 cols x 4 planes each)

typedef decltype(__builtin_amdgcn_cvt_pkrtz(0.f, 0.f)) h2;
typedef float f4 __attribute__((ext_vector_type(4)));
typedef _Float16 h8 __attribute__((ext_vector_type(8)));   // 16B LDS vector

union H8U { h8 v; h2 h[4]; };

// VOP3P dot2 (cannot address AGPRs -> keeps accumulate on arch VGPRs at use)
__device__ __forceinline__ void dot2a(float& c, h2 a, h2 b) {
    asm("v_dot2_f32_f16 %0, %1, %2, %0" : "+v"(c) : "v"(a), "v"(b));
}

__device__ __forceinline__ void barrier_nb() {
    // lgkmcnt(0) only: LDS writes visible; global loads stay in flight
    asm volatile("s_waitcnt lgkmcnt(0)" ::: "memory");
    __builtin_amdgcn_s_barrier();
    asm volatile("" ::: "memory");
}

__global__ __launch_bounds__(NTHR)
__attribute__((amdgpu_waves_per_eu(1)))   // min 1 wave/EU: full reg budget, no AGPR squeeze
void mov_kernel(const float* __restrict__ q, const float* __restrict__ k,
                float* __restrict__ out) {
    const int tid = threadIdx.x;
    const int tx  = tid & 15;          // 16 pixel-pairs wide
    const int ty  = tid >> 4;          // 16 rows
    // XCD-aware decode: all 18 tiles of one (b, head) slice share one XCD
    const int bid  = blockIdx.x;       // 0..1151
    const int n    = bid & 7;
    const int t2   = bid >> 3;
    const int b    = t2 / 18;
    const int tile = t2 - b * 18;
    const int th_i = tile / 3;
    const int tw_i = tile - th_i * 3;
    const int h0 = th_i * TH, w0 = tw_i * TW;
    const int h = h0 + ty, w = w0 + 2 * tx;

    __shared__ h2 lk[2 * LKSZ];

    // ---- staging task: 1 per thread (tid < 220): row r, col-group g ----
    const bool sv = (tid < TASKS);
    const int r_  = sv ? tid / 10 : 0;
    const int g_  = sv ? tid - r_ * 10 : 0;
    const int y_  = min(max(h0 + r_ - AMP, 0), HH - 1);
    const int sgo = y_ * WW + (w0 - 4 + 4 * g_);       // global offset in plane
    const int slo = r_ * ROWH2 + 8 * g_;               // LDS h2 offset

    const int kbase = (b * CC + n) * PLANE;
    const int qoff  = kbase + h * WW + w;
    const float scale = 0.125f;

    float acc0[KS * KS], acc1[KS * KS];
#pragma unroll
    for (int o = 0; o < KS * KS; ++o) { acc0[o] = 0.f; acc1[o] = 0.f; }

    f4 ka, kb, kc, kd;     // 4 planes of this task's 4 cols
    float2 qv[4];          // this chunk's 4 q planes (2 pixels each)

    auto LOADK = [&](int c) {
        if (sv) {
            int base = kbase + c * 4 * NPLANE + sgo;
            int i0 = min(max(base,              0), NTOT - 4);
            int i1 = min(max(base +     NPLANE, 0), NTOT - 4);
            int i2 = min(max(base + 2 * NPLANE, 0), NTOT - 4);
            int i3 = min(max(base + 3 * NPLANE, 0), NTOT - 4);
            ka = *(const f4*)(k + i0);
            kb = *(const f4*)(k + i1);
            kc = *(const f4*)(k + i2);
            kd = *(const f4*)(k + i3);
        }
    };
    auto LOADQ = [&](int c) {
#pragma unroll
        for (int d = 0; d < 4; ++d)
            qv[d] = *(const float2*)(q + qoff + (c * 4 + d) * NPLANE);
    };
    auto WRITEK = [&](int buf) {
        if (sv) {
            H8U u0, u1;
            u0.h[0] = __builtin_amdgcn_cvt_pkrtz(ka.x, kb.x);  // col0 pair0
            u0.h[1] = __builtin_amdgcn_cvt_pkrtz(kc.x, kd.x);  // col0 pair1
            u0.h[2] = __builtin_amdgcn_cvt_pkrtz(ka.y, kb.y);
            u0.h[3] = __builtin_amdgcn_cvt_pkrtz(kc.y, kd.y);
            u1.h[0] = __builtin_amdgcn_cvt_pkrtz(ka.z, kb.z);
            u1.h[1] = __builtin_amdgcn_cvt_pkrtz(kc.z, kd.z);
            u1.h[2] = __builtin_amdgcn_cvt_pkrtz(ka.w, kb.w);
            u1.h[3] = __builtin_amdgcn_cvt_pkrtz(kc.w, kd.w);
            h2* dst = &lk[buf * LKSZ + slo];
            *(h8*)(dst)     = u0.v;
            *(h8*)(dst + 4) = u1.v;
        }
    };

    LOADK(0);
    LOADQ(0);
    for (int c = 0; c < NCHUNK; ++c) {
        const int buf = c & 1;
        WRITEK(buf);                       // vmcnt-waits this chunk's k loads
        if (c + 1 < NCHUNK) LOADK(c + 1);
        // pack q: A = planes(d0,d1), B = planes(d2,d3); 0 = px0, 1 = px1
        h2 qA0 = __builtin_amdgcn_cvt_pkrtz(qv[0].x * scale, qv[1].x * scale);
        h2 qB0 = __builtin_amdgcn_cvt_pkrtz(qv[2].x * scale, qv[3].x * scale);
        h2 qA1 = __builtin_amdgcn_cvt_pkrtz(qv[0].y * scale, qv[1].y * scale);
        h2 qB1 = __builtin_amdgcn_cvt_pkrtz(qv[2].y * scale, qv[3].y * scale);
        if (c + 1 < NCHUNK) LOADQ(c + 1);
        barrier_nb();                      // buf fully written, then read
        // ---- per halo row i: 5x ds_read_b128 -> 28 dot2 ----
#pragma unroll
        for (int i = 0; i < KS; ++i) {
            const h2* row = &lk[buf * LKSZ + (ty + i) * ROWH2 + 4 * tx];
            h2 kvA[10], kvB[10];
#pragma unroll
            for (int m = 0; m < 5; ++m) {
                H8U u; u.v = *(const h8*)(row + 4 * m);
                kvA[2 * m]     = u.h[0];   // col 2m,   pair0
                kvB[2 * m]     = u.h[1];   // col 2m,   pair1
                kvA[2 * m + 1] = u.h[2];
                kvB[2 * m + 1] = u.h[3];
            }
#pragma unroll
            for (int j = 0; j < KS; ++j) {
                dot2a(acc0[i * KS + j], qA0, kvA[j + 1]);
                dot2a(acc0[i * KS + j], qB0, kvB[j + 1]);
                dot2a(acc1[i * KS + j], qA1, kvA[j + 2]);
                dot2a(acc1[i * KS + j], qB1, kvB[j + 2]);
            }
        }
        // no trailing barrier: buf is next overwritten at c+2, which is
        // already ordered after barrier(c+1) -> double buffer is race-free
    }

    // ---- mask invalid offsets (reference: -1000 -> exp == 0) ----
#pragma unroll
    for (int i = 0; i < KS; ++i) {
        bool vi = ((unsigned)(h + i - AMP) < HH);
#pragma unroll
        for (int j = 0; j < KS; ++j) {
            bool v0 = vi && ((unsigned)(w + j - AMP) < WW);
            bool v1 = vi && ((unsigned)(w + 1 + j - AMP) < WW);
            if (!v0) acc0[i * KS + j] = -1e30f;
            if (!v1) acc1[i * KS + j] = -1e30f;
        }
    }

    // ---- softmax over 49 offsets + expectation of (di, dj) ----
    float m0 = -1e30f, m1 = -1e30f;
#pragma unroll
    for (int o = 0; o < KS * KS; ++o) {
        m0 = fmaxf(m0, acc0[o]);
        m1 = fmaxf(m1, acc1[o]);
    }
    float l0 = 0.f, di0 = 0.f, dj0 = 0.f;
    float l1 = 0.f, di1 = 0.f, dj1 = 0.f;
#pragma unroll
    for (int i = 0; i < KS; ++i) {
#pragma unroll
        for (int j = 0; j < KS; ++j) {
            float e0 = __expf(acc0[i * KS + j] - m0);
            float e1 = __expf(acc1[i * KS + j] - m1);
            l0 += e0; l1 += e1;
            di0 += e0 * (float)(i - AMP);
            di1 += e1 * (float)(i - AMP);
            dj0 += e0 * (float)(j - AMP);
            dj1 += e1 * (float)(j - AMP);
        }
    }
    float inv0 = 1.0f / (l0 * (float)NH);
    float inv1 = 1.0f / (l1 * (float)NH);

    float* o0 = out + ((size_t)b * 2 + 0) * PLANE + h * WW + w;
    float* o1 = out + ((size_t)b * 2 + 1) * PLANE + h * WW + w;
    atomicAdd(o0,     di0 * inv0);
    atomicAdd(o0 + 1, di1 * inv1);
    atomicAdd(o1,     dj0 * inv0);
    atomicAdd(o1 + 1, dj1 * inv1);
}

extern "C" void kernel_launch(void* const* d_in, const int* in_sizes, int n_in,
                              void* d_out, int out_size, void* d_ws, size_t ws_size,
                              hipStream_t stream) {
    const float* q = (const float*)d_in[0];
    const float* k = (const float*)d_in[1];
    float* out = (float*)d_out;

    hipMemsetAsync(out, 0, (size_t)out_size * sizeof(float), stream);

    dim3 grid(BB * NH * (HH / TH) * (WW / TW));   // 1152
    dim3 block(NTHR);
    hipLaunchKernelGGL(mov_kernel, grid, block, 0, stream, q, k, out);
}